// Round 6
// baseline (151.926 us; speedup 1.0000x reference)
//
#include <hip/hip_runtime.h>

#define MARGIN 0.3f
#define INF_BITS 0x7f800000
#define NINF_BITS 0xff800000

typedef __attribute__((ext_vector_type(8))) short bf16x8;
typedef __attribute__((ext_vector_type(4))) float f32x4;

__device__ inline unsigned short f2bf(float x) {
    unsigned int u = __float_as_uint(x);
    unsigned int r = (u + 0x7fffu + ((u >> 16) & 1u)) >> 16;
    return (unsigned short)r;
}

__device__ __forceinline__ void gload16(const unsigned short* g, char* l) {
    __builtin_amdgcn_global_load_lds(
        (const __attribute__((address_space(1))) void*)g,
        (__attribute__((address_space(3))) void*)l, 16, 0, 0);
}

// stage one 128x64 half-tile: this thread's 2 chunks (rows r0 and r0+64)
__device__ __forceinline__ void stage_half(const unsigned short* g, char* l) {
    gload16(g, l);                 // row r0
    gload16(g + 65536, l + 8192);  // row r0+64
}

// ---------------------------------------------------------------------------
// Kernel 1: fp32 -> bf16 cast + per-row norms (wave per row) + red/cnt init.
// ---------------------------------------------------------------------------
__global__ void __launch_bounds__(256) prep_kernel(
    const float* __restrict__ in, unsigned short* __restrict__ bf,
    float* __restrict__ norms, int* __restrict__ red)
{
    const int wid = threadIdx.x >> 6, lane = threadIdx.x & 63;
    const int row = blockIdx.x * 4 + wid;
    const size_t base = (size_t)row * 1024;
    float s = 0.f;
    #pragma unroll
    for (int k = 0; k < 4; ++k) {
        const float4 v = ((const float4*)(in + base))[lane + 64 * k];
        s += v.x * v.x + v.y * v.y + v.z * v.z + v.w * v.w;
        ushort4 o;
        o.x = f2bf(v.x); o.y = f2bf(v.y); o.z = f2bf(v.z); o.w = f2bf(v.w);
        ((ushort4*)(bf + base))[lane + 64 * k] = o;
    }
    #pragma unroll
    for (int off = 32; off > 0; off >>= 1) s += __shfl_down(s, off);
    if (lane == 0) norms[row] = s;
    if (blockIdx.x < 64) {
        int i = blockIdx.x * 256 + threadIdx.x;   // 0..16383
        red[i] = ((i >> 12) & 1) ? INF_BITS : 0;
    }
    if (blockIdx.x == 0 && threadIdx.x == 0) red[16384] = 0;  // done-counter
}

// ---------------------------------------------------------------------------
// Kernel 2: 256x256-tile, 8-phase bf16 MFMA GEMM + fused masked reductions
// + last-block final loss.
// ---------------------------------------------------------------------------
#define VM_WAIT(n) asm volatile("s_waitcnt vmcnt(" #n ")" ::: "memory")

#define STAGE_A(h, kt, b) \
    stage_half(pA + (h)*131072 + ((kt) << 6), lds + (b)*65536 + (h)*16384 + tid*16)
#define STAGE_B(h, kt, b) \
    stage_half(pB + (h)*131072 + ((kt) << 6), lds + (b)*65536 + 32768 + (h)*16384 + tid*16)

#define PHASE(qq, bc, STAGE_STMT, WAIT_STMT)                                     \
  {                                                                              \
    const char* ab = lds + (bc) * 65536 + aoff + (2 * (qq)) * 2048;              \
    bf16x8 a0k0 = *(const bf16x8*)(ab + swz0);                                   \
    bf16x8 a0k1 = *(const bf16x8*)(ab + swz1);                                   \
    bf16x8 a1k0 = *(const bf16x8*)(ab + 2048 + swz0);                            \
    bf16x8 a1k1 = *(const bf16x8*)(ab + 2048 + swz1);                            \
    if ((qq) == 0) {                                                             \
      const char* bb = lds + (bc) * 65536 + boff;                                \
      _Pragma("unroll")                                                          \
      for (int n = 0; n < 4; ++n) {                                              \
        bk0[n] = *(const bf16x8*)(bb + n * 2048 + swz0);                         \
        bk1[n] = *(const bf16x8*)(bb + n * 2048 + swz1);                         \
      }                                                                          \
    }                                                                            \
    STAGE_STMT;                                                                  \
    if ((qq) == 0) asm volatile("s_waitcnt lgkmcnt(8)" ::: "memory");            \
    __builtin_amdgcn_s_barrier();                                                \
    asm volatile("s_waitcnt lgkmcnt(0)" ::: "memory");                           \
    __builtin_amdgcn_sched_barrier(0);                                           \
    __builtin_amdgcn_s_setprio(1);                                               \
    _Pragma("unroll")                                                            \
    for (int n = 0; n < 4; ++n) {                                                \
      acc[2*(qq)][n]   = __builtin_amdgcn_mfma_f32_16x16x32_bf16(a0k0, bk0[n], acc[2*(qq)][n], 0, 0, 0);   \
      acc[2*(qq)+1][n] = __builtin_amdgcn_mfma_f32_16x16x32_bf16(a1k0, bk0[n], acc[2*(qq)+1][n], 0, 0, 0); \
    }                                                                            \
    _Pragma("unroll")                                                            \
    for (int n = 0; n < 4; ++n) {                                                \
      acc[2*(qq)][n]   = __builtin_amdgcn_mfma_f32_16x16x32_bf16(a0k1, bk1[n], acc[2*(qq)][n], 0, 0, 0);   \
      acc[2*(qq)+1][n] = __builtin_amdgcn_mfma_f32_16x16x32_bf16(a1k1, bk1[n], acc[2*(qq)+1][n], 0, 0, 0); \
    }                                                                            \
    __builtin_amdgcn_s_setprio(0);                                               \
    WAIT_STMT;                                                                   \
    __builtin_amdgcn_s_barrier();                                                \
  }

__global__ void __launch_bounds__(512, 2) dist_kernel(
    const unsigned short* __restrict__ Abf, const unsigned short* __restrict__ Bbf,
    const float* __restrict__ na, const float* __restrict__ nb,
    const int* __restrict__ tgt,
    int* __restrict__ g_rgb_ap, int* __restrict__ g_rgb_an,
    int* __restrict__ g_ir_ap, int* __restrict__ g_ir_an,
    int* __restrict__ g_cnt, float* __restrict__ g_out)
{
    extern __shared__ char lds[];
    __shared__ int lastBlk;

    const int tid  = threadIdx.x;
    const int lane = tid & 63;
    const int wid  = tid >> 6;          // 0..7
    const int wr   = wid >> 2;          // 0..1  (M)
    const int wc   = wid & 3;           // 0..3  (N)
    const int l4 = lane >> 4, rsel = lane & 15;

    // XCD-bijective swizzle: each XCD gets a 4(brow) x 8(bcol) region.
    const int lin = blockIdx.y * 16 + blockIdx.x;
    const int xcd = lin & 7, idx = lin >> 3;
    const int brow = (xcd >> 1) * 4 + (idx >> 3);
    const int bcol = (xcd & 1) * 8 + (idx & 7);

    // staging addresses (swizzle on the GLOBAL source column; LDS linear)
    const int r0 = tid >> 3;
    const int cs = (tid & 7) << 4;
    const int c0 = (cs ^ ((r0 & 7) << 4)) >> 1;
    const unsigned short* pA = Abf + (size_t)(brow * 256 + r0) * 1024 + c0;
    const unsigned short* pB = Bbf + (size_t)(bcol * 256 + r0) * 1024 + c0;

    // ds_read offsets (swizzled to match)
    const int swz0 = ((l4 ^ (rsel & 7)) << 4);
    const int swz1 = (((4 + l4) ^ (rsel & 7)) << 4);
    const int aoff = wr * 16384 + rsel * 128;
    const int boff = 32768 + (wc >> 1) * 16384 + (wc & 1) * 8192 + rsel * 128;

    f32x4 acc[8][4];
    const f32x4 zero = {0.f, 0.f, 0.f, 0.f};
    #pragma unroll
    for (int m = 0; m < 8; ++m)
        #pragma unroll
        for (int n = 0; n < 4; ++n)
            acc[m][n] = zero;

    bf16x8 bk0[4], bk1[4];

    // prologue: K0 full -> buf0, K1 B-halves -> buf1; drain only K0
    STAGE_A(0, 0, 0); STAGE_A(1, 0, 0);
    STAGE_B(0, 0, 0); STAGE_B(1, 0, 0);
    STAGE_B(0, 1, 1); STAGE_B(1, 1, 1);
    VM_WAIT(4);
    __builtin_amdgcn_s_barrier();

    // main loop: K-tiles staged exactly once each (A 1..14, B 2..15 here;
    // A15 staged in the tail; no wrapped stages)
    for (int i = 0; i < 7; ++i) {
        const int t = 2 * i;
        PHASE(0, 0, STAGE_A(0, t + 1, 1), );
        PHASE(1, 0, STAGE_A(1, t + 1, 1), );
        PHASE(2, 0, STAGE_B(0, t + 2, 0), );
        PHASE(3, 0, STAGE_B(1, t + 2, 0), VM_WAIT(4));
        PHASE(0, 1, STAGE_A(0, t + 2, 0), );
        PHASE(1, 1, STAGE_A(1, t + 2, 0), );
        PHASE(2, 1, STAGE_B(0, t + 3, 1), );
        PHASE(3, 1, STAGE_B(1, t + 3, 1), VM_WAIT(4));
    }

    // tail (t = 14): only A(15) remains to stage; full drain before buf1 reads
    PHASE(0, 0, STAGE_A(0, 15, 1), );
    PHASE(1, 0, STAGE_A(1, 15, 1), );
    PHASE(2, 0, , );
    PHASE(3, 0, , VM_WAIT(0));
    PHASE(0, 1, , );
    PHASE(1, 1, , );
    PHASE(2, 1, , );
    PHASE(3, 1, , );

    // ---------------- fused epilogue (sq-space reductions) ----------------
    __syncthreads();

    char* rowbase = lds;                       // 256*528 = 135168 B
    float* colMax = (float*)(lds + 135168);    // 9216 B
    float* colMin = (float*)(lds + 144384);    // 9216 B

    const float NINF = __int_as_float((int)NINF_BITS);
    const float PINF = __int_as_float(INF_BITS);

    int jg[4], ltc[4];
    float nbv[4];
    #pragma unroll
    for (int n = 0; n < 4; ++n) {
        jg[n] = bcol * 256 + wc * 64 + n * 16 + rsel;
        ltc[n] = tgt[jg[n]];
        nbv[n] = nb[jg[n]];
    }

    float cmax[4] = {NINF, NINF, NINF, NINF};
    float cmin[4] = {PINF, PINF, PINF, PINF};

    #pragma unroll
    for (int m = 0; m < 8; ++m) {
        #pragma unroll
        for (int r = 0; r < 4; ++r) {
            const int lrow = wr * 128 + m * 16 + l4 * 4 + r;
            const int ig = brow * 256 + lrow;
            const int lt = tgt[4096 + ig];
            const float nav = na[ig];
            float rx = NINF, rn = PINF;
            #pragma unroll
            for (int n = 0; n < 4; ++n) {
                const float urow = __builtin_fmaf(-2.0f, acc[m][n][r], nbv[n]);
                const float ucol = __builtin_fmaf(-2.0f, acc[m][n][r], nav);
                const bool match = (ltc[n] == lt);
                rx = match ? fmaxf(rx, urow) : rx;
                rn = match ? rn : fminf(rn, urow);
                cmax[n] = match ? fmaxf(cmax[n], ucol) : cmax[n];
                cmin[n] = match ? cmin[n] : fminf(cmin[n], ucol);
            }
            float2* rp = (float2*)(rowbase + lrow * 528 + (wc * 16 + rsel) * 8);
            *rp = make_float2(rx, rn);
        }
    }
    #pragma unroll
    for (int n = 0; n < 4; ++n) {
        const int lcol = wc * 64 + n * 16 + rsel;
        colMax[lcol * 9 + wr * 4 + l4] = cmax[n];
        colMin[lcol * 9 + wr * 4 + l4] = cmin[n];
    }
    __syncthreads();

    if (tid < 256) {
        // row reduce: partials are (nb_j - 2dot); add na, clip, sqrt, atomic
        const int row = tid;
        const f32x4* rp = (const f32x4*)(rowbase + row * 528);
        float rmax = NINF, rmin = PINF;
        #pragma unroll 8
        for (int s = 0; s < 32; ++s) {
            const f32x4 v = rp[s];
            rmax = fmaxf(rmax, fmaxf(v[0], v[2]));
            rmin = fminf(rmin, fminf(v[1], v[3]));
        }
        const int ig = brow * 256 + row;
        const float nav = na[ig];
        const float ap = sqrtf(fmaxf(nav + rmax, 1e-12f));
        const float an = sqrtf(fmaxf(nav + rmin, 1e-12f));
        atomicMax(&g_rgb_ap[ig], __float_as_int(ap));
        atomicMin(&g_rgb_an[ig], __float_as_int(an));
    } else {
        // col reduce: partials are (na_i - 2dot); add nb, clip, sqrt, atomic
        const int col = tid & 255;
        float cm = NINF, cn = PINF;
        #pragma unroll
        for (int s = 0; s < 8; ++s) {
            cm = fmaxf(cm, colMax[col * 9 + s]);
            cn = fminf(cn, colMin[col * 9 + s]);
        }
        const int jgc = bcol * 256 + col;
        const float nbc = nb[jgc];
        const float ap = sqrtf(fmaxf(nbc + cm, 1e-12f));
        const float an = sqrtf(fmaxf(nbc + cn, 1e-12f));
        atomicMax(&g_ir_ap[jgc], __float_as_int(ap));
        atomicMin(&g_ir_an[jgc], __float_as_int(an));
    }

    // ---------------- last-block final loss ----------------
    __threadfence();
    if (tid == 0) lastBlk = (atomicAdd(g_cnt, 1) == 255);
    __syncthreads();
    if (!lastBlk) return;
    __threadfence();

    float s = 0.f;
    #pragma unroll
    for (int k = 0; k < 8; ++k) {
        const int i = k * 512 + tid;
        // RMW reads: coherent across XCD L2s (plain loads could be stale)
        const float ap  = __int_as_float(atomicOr(&g_rgb_ap[i], 0));
        const float an  = __int_as_float(atomicOr(&g_rgb_an[i], 0));
        const float ap2 = __int_as_float(atomicOr(&g_ir_ap[i], 0));
        const float an2 = __int_as_float(atomicOr(&g_ir_an[i], 0));
        s += fmaxf(0.f, MARGIN - (an - ap)) + fmaxf(0.f, MARGIN - (an2 - ap2));
    }
    #pragma unroll
    for (int off = 32; off > 0; off >>= 1) s += __shfl_down(s, off);
    float* wsum = (float*)lds;   // GEMM/epilogue LDS is dead now
    __syncthreads();
    if ((tid & 63) == 0) wsum[tid >> 6] = s;
    __syncthreads();
    if (tid == 0) {
        float t = 0.f;
        #pragma unroll
        for (int w = 0; w < 8; ++w) t += wsum[w];
        g_out[0] = t / 4096.0f;
    }
}

// ---------------------------------------------------------------------------
extern "C" void kernel_launch(void* const* d_in, const int* in_sizes, int n_in,
                              void* d_out, int out_size, void* d_ws, size_t ws_size,
                              hipStream_t stream) {
    (void)in_sizes; (void)n_in; (void)out_size; (void)ws_size;
    const float* input = (const float*)d_in[0];
    const int* tgt = (const int*)d_in[1];
    float* out = (float*)d_out;

    unsigned short* bf = (unsigned short*)d_ws;
    float* norms = (float*)(bf + (size_t)8192 * 1024);
    int* red = (int*)(norms + 8192);          // 16384 ints + 1 counter

    hipFuncSetAttribute((const void*)dist_kernel,
                        hipFuncAttributeMaxDynamicSharedMemorySize, 153600);

    prep_kernel<<<2048, 256, 0, stream>>>(input, bf, norms, red);
    dist_kernel<<<dim3(16, 16), 512, 153600, stream>>>(
        bf, bf + (size_t)4096 * 1024, norms, norms + 4096, tgt,
        red, red + 4096, red + 8192, red + 12288,
        red + 16384, out);
}

// Round 7
// 48.885 us; speedup vs baseline: 3.1078x; 3.1078x over previous
//
#include <hip/hip_runtime.h>

#define MARGIN 0.3f
#define INF_BITS 0x7f800000
#define NINF_BITS 0xff800000

typedef __attribute__((ext_vector_type(8))) short bf16x8;
typedef __attribute__((ext_vector_type(4))) float f32x4;

__device__ inline unsigned short f2bf(float x) {
    unsigned int u = __float_as_uint(x);
    unsigned int r = (u + 0x7fffu + ((u >> 16) & 1u)) >> 16;
    return (unsigned short)r;
}

__device__ __forceinline__ void gload16(const unsigned short* g, char* l) {
    __builtin_amdgcn_global_load_lds(
        (const __attribute__((address_space(1))) void*)g,
        (__attribute__((address_space(3))) void*)l, 16, 0, 0);
}

// stage one 128x64 half-tile: this thread's 2 chunks (rows r0 and r0+64)
__device__ __forceinline__ void stage_half(const unsigned short* g, char* l) {
    gload16(g, l);                 // row r0
    gload16(g + 65536, l + 8192);  // row r0+64
}

// ---------------------------------------------------------------------------
// Kernel 1: fp32 -> bf16 cast + per-row norms (wave per row) + red/cnt init.
// ---------------------------------------------------------------------------
__global__ void __launch_bounds__(256) prep_kernel(
    const float* __restrict__ in, unsigned short* __restrict__ bf,
    float* __restrict__ norms, int* __restrict__ red)
{
    const int wid = threadIdx.x >> 6, lane = threadIdx.x & 63;
    const int row = blockIdx.x * 4 + wid;
    const size_t base = (size_t)row * 1024;
    float s = 0.f;
    #pragma unroll
    for (int k = 0; k < 4; ++k) {
        const float4 v = ((const float4*)(in + base))[lane + 64 * k];
        s += v.x * v.x + v.y * v.y + v.z * v.z + v.w * v.w;
        ushort4 o;
        o.x = f2bf(v.x); o.y = f2bf(v.y); o.z = f2bf(v.z); o.w = f2bf(v.w);
        ((ushort4*)(bf + base))[lane + 64 * k] = o;
    }
    #pragma unroll
    for (int off = 32; off > 0; off >>= 1) s += __shfl_down(s, off);
    if (lane == 0) norms[row] = s;
    if (blockIdx.x < 64) {
        int i = blockIdx.x * 256 + threadIdx.x;   // 0..16383
        red[i] = ((i >> 12) & 1) ? INF_BITS : 0;
    }
    if (blockIdx.x == 0 && threadIdx.x == 0) red[16384] = 0;  // done-counter
}

// ---------------------------------------------------------------------------
// Kernel 2: 256x256-tile, 8-phase bf16 MFMA GEMM + fused masked reductions
// + fence-free last-block final loss.
// ---------------------------------------------------------------------------
#define VM_WAIT(n) asm volatile("s_waitcnt vmcnt(" #n ")" ::: "memory")

#define STAGE_A(h, kt, b) \
    stage_half(pA + (h)*131072 + ((kt) << 6), lds + (b)*65536 + (h)*16384 + tid*16)
#define STAGE_B(h, kt, b) \
    stage_half(pB + (h)*131072 + ((kt) << 6), lds + (b)*65536 + 32768 + (h)*16384 + tid*16)

#define PHASE(qq, bc, STAGE_STMT, WAIT_STMT)                                     \
  {                                                                              \
    const char* ab = lds + (bc) * 65536 + aoff + (2 * (qq)) * 2048;              \
    bf16x8 a0k0 = *(const bf16x8*)(ab + swz0);                                   \
    bf16x8 a0k1 = *(const bf16x8*)(ab + swz1);                                   \
    bf16x8 a1k0 = *(const bf16x8*)(ab + 2048 + swz0);                            \
    bf16x8 a1k1 = *(const bf16x8*)(ab + 2048 + swz1);                            \
    if ((qq) == 0) {                                                             \
      const char* bb = lds + (bc) * 65536 + boff;                                \
      _Pragma("unroll")                                                          \
      for (int n = 0; n < 4; ++n) {                                              \
        bk0[n] = *(const bf16x8*)(bb + n * 2048 + swz0);                         \
        bk1[n] = *(const bf16x8*)(bb + n * 2048 + swz1);                         \
      }                                                                          \
    }                                                                            \
    STAGE_STMT;                                                                  \
    if ((qq) == 0) asm volatile("s_waitcnt lgkmcnt(8)" ::: "memory");            \
    __builtin_amdgcn_s_barrier();                                                \
    asm volatile("s_waitcnt lgkmcnt(0)" ::: "memory");                           \
    __builtin_amdgcn_sched_barrier(0);                                           \
    __builtin_amdgcn_s_setprio(1);                                               \
    _Pragma("unroll")                                                            \
    for (int n = 0; n < 4; ++n) {                                                \
      acc[2*(qq)][n]   = __builtin_amdgcn_mfma_f32_16x16x32_bf16(a0k0, bk0[n], acc[2*(qq)][n], 0, 0, 0);   \
      acc[2*(qq)+1][n] = __builtin_amdgcn_mfma_f32_16x16x32_bf16(a1k0, bk0[n], acc[2*(qq)+1][n], 0, 0, 0); \
    }                                                                            \
    _Pragma("unroll")                                                            \
    for (int n = 0; n < 4; ++n) {                                                \
      acc[2*(qq)][n]   = __builtin_amdgcn_mfma_f32_16x16x32_bf16(a0k1, bk1[n], acc[2*(qq)][n], 0, 0, 0);   \
      acc[2*(qq)+1][n] = __builtin_amdgcn_mfma_f32_16x16x32_bf16(a1k1, bk1[n], acc[2*(qq)+1][n], 0, 0, 0); \
    }                                                                            \
    __builtin_amdgcn_s_setprio(0);                                               \
    WAIT_STMT;                                                                   \
    __builtin_amdgcn_s_barrier();                                                \
  }

__global__ void __launch_bounds__(512, 2) dist_kernel(
    const unsigned short* __restrict__ Abf, const unsigned short* __restrict__ Bbf,
    const float* __restrict__ na, const float* __restrict__ nb,
    const int* __restrict__ tgt,
    int* __restrict__ g_rgb_ap, int* __restrict__ g_rgb_an,
    int* __restrict__ g_ir_ap, int* __restrict__ g_ir_an,
    int* __restrict__ g_cnt, float* __restrict__ g_out)
{
    extern __shared__ char lds[];

    const int tid  = threadIdx.x;
    const int lane = tid & 63;
    const int wid  = tid >> 6;          // 0..7
    const int wr   = wid >> 2;          // 0..1  (M)
    const int wc   = wid & 3;           // 0..3  (N)
    const int l4 = lane >> 4, rsel = lane & 15;

    // XCD-bijective swizzle: each XCD gets a 4(brow) x 8(bcol) region.
    const int lin = blockIdx.y * 16 + blockIdx.x;
    const int xcd = lin & 7, idx = lin >> 3;
    const int brow = (xcd >> 1) * 4 + (idx >> 3);
    const int bcol = (xcd & 1) * 8 + (idx & 7);

    // staging addresses (swizzle on the GLOBAL source column; LDS linear)
    const int r0 = tid >> 3;
    const int cs = (tid & 7) << 4;
    const int c0 = (cs ^ ((r0 & 7) << 4)) >> 1;
    const unsigned short* pA = Abf + (size_t)(brow * 256 + r0) * 1024 + c0;
    const unsigned short* pB = Bbf + (size_t)(bcol * 256 + r0) * 1024 + c0;

    // ds_read offsets (swizzled to match)
    const int swz0 = ((l4 ^ (rsel & 7)) << 4);
    const int swz1 = (((4 + l4) ^ (rsel & 7)) << 4);
    const int aoff = wr * 16384 + rsel * 128;
    const int boff = 32768 + (wc >> 1) * 16384 + (wc & 1) * 8192 + rsel * 128;

    f32x4 acc[8][4];
    const f32x4 zero = {0.f, 0.f, 0.f, 0.f};
    #pragma unroll
    for (int m = 0; m < 8; ++m)
        #pragma unroll
        for (int n = 0; n < 4; ++n)
            acc[m][n] = zero;

    bf16x8 bk0[4], bk1[4];

    // prologue: K0 full -> buf0, K1 B-halves -> buf1; drain only K0
    STAGE_A(0, 0, 0); STAGE_A(1, 0, 0);
    STAGE_B(0, 0, 0); STAGE_B(1, 0, 0);
    STAGE_B(0, 1, 1); STAGE_B(1, 1, 1);
    VM_WAIT(4);
    __builtin_amdgcn_s_barrier();

    // main loop: K-tiles staged exactly once each (A 1..14, B 2..15 here;
    // A15 staged in the tail; no wrapped stages)
    for (int i = 0; i < 7; ++i) {
        const int t = 2 * i;
        PHASE(0, 0, STAGE_A(0, t + 1, 1), );
        PHASE(1, 0, STAGE_A(1, t + 1, 1), );
        PHASE(2, 0, STAGE_B(0, t + 2, 0), );
        PHASE(3, 0, STAGE_B(1, t + 2, 0), VM_WAIT(4));
        PHASE(0, 1, STAGE_A(0, t + 2, 0), );
        PHASE(1, 1, STAGE_A(1, t + 2, 0), );
        PHASE(2, 1, STAGE_B(0, t + 3, 1), );
        PHASE(3, 1, STAGE_B(1, t + 3, 1), VM_WAIT(4));
    }

    // tail (t = 14): only A(15) remains to stage; full drain before buf1 reads
    PHASE(0, 0, STAGE_A(0, 15, 1), );
    PHASE(1, 0, STAGE_A(1, 15, 1), );
    PHASE(2, 0, , );
    PHASE(3, 0, , VM_WAIT(0));
    PHASE(0, 1, , );
    PHASE(1, 1, , );
    PHASE(2, 1, , );
    PHASE(3, 1, , );

    // ---------------- fused epilogue (sq-space reductions) ----------------
    __syncthreads();

    char* rowbase = lds;                       // 256*528 = 135168 B
    float* colMax = (float*)(lds + 135168);    // 9216 B
    float* colMin = (float*)(lds + 144384);    // 9216 B

    const float NINF = __int_as_float((int)NINF_BITS);
    const float PINF = __int_as_float(INF_BITS);

    int jg[4], ltc[4];
    float nbv[4];
    #pragma unroll
    for (int n = 0; n < 4; ++n) {
        jg[n] = bcol * 256 + wc * 64 + n * 16 + rsel;
        ltc[n] = tgt[jg[n]];
        nbv[n] = nb[jg[n]];
    }

    float cmax[4] = {NINF, NINF, NINF, NINF};
    float cmin[4] = {PINF, PINF, PINF, PINF};

    #pragma unroll
    for (int m = 0; m < 8; ++m) {
        #pragma unroll
        for (int r = 0; r < 4; ++r) {
            const int lrow = wr * 128 + m * 16 + l4 * 4 + r;
            const int ig = brow * 256 + lrow;
            const int lt = tgt[4096 + ig];
            const float nav = na[ig];
            float rx = NINF, rn = PINF;
            #pragma unroll
            for (int n = 0; n < 4; ++n) {
                const float urow = __builtin_fmaf(-2.0f, acc[m][n][r], nbv[n]);
                const float ucol = __builtin_fmaf(-2.0f, acc[m][n][r], nav);
                const bool match = (ltc[n] == lt);
                rx = match ? fmaxf(rx, urow) : rx;
                rn = match ? rn : fminf(rn, urow);
                cmax[n] = match ? fmaxf(cmax[n], ucol) : cmax[n];
                cmin[n] = match ? cmin[n] : fminf(cmin[n], ucol);
            }
            float2* rp = (float2*)(rowbase + lrow * 528 + (wc * 16 + rsel) * 8);
            *rp = make_float2(rx, rn);
        }
    }
    #pragma unroll
    for (int n = 0; n < 4; ++n) {
        const int lcol = wc * 64 + n * 16 + rsel;
        colMax[lcol * 9 + wr * 4 + l4] = cmax[n];
        colMin[lcol * 9 + wr * 4 + l4] = cmin[n];
    }
    __syncthreads();

    if (tid < 256) {
        // row reduce: partials are (nb_j - 2dot); add na, clip, sqrt, atomic
        const int row = tid;
        const f32x4* rp = (const f32x4*)(rowbase + row * 528);
        float rmax = NINF, rmin = PINF;
        #pragma unroll 8
        for (int s = 0; s < 32; ++s) {
            const f32x4 v = rp[s];
            rmax = fmaxf(rmax, fmaxf(v[0], v[2]));
            rmin = fminf(rmin, fminf(v[1], v[3]));
        }
        const int ig = brow * 256 + row;
        const float nav = na[ig];
        const float ap = sqrtf(fmaxf(nav + rmax, 1e-12f));
        const float an = sqrtf(fmaxf(nav + rmin, 1e-12f));
        // keep RMW returns live: forces sc0 form so vmcnt retirement proves
        // completion at the device coherence point (fence-free ordering)
        int o0 = atomicMax(&g_rgb_ap[ig], __float_as_int(ap));
        int o1 = atomicMin(&g_rgb_an[ig], __float_as_int(an));
        asm volatile("" :: "v"(o0), "v"(o1));
    } else {
        // col reduce: partials are (na_i - 2dot); add nb, clip, sqrt, atomic
        const int col = tid & 255;
        float cm = NINF, cn = PINF;
        #pragma unroll
        for (int s = 0; s < 8; ++s) {
            cm = fmaxf(cm, colMax[col * 9 + s]);
            cn = fminf(cn, colMin[col * 9 + s]);
        }
        const int jgc = bcol * 256 + col;
        const float nbc = nb[jgc];
        const float ap = sqrtf(fmaxf(nbc + cm, 1e-12f));
        const float an = sqrtf(fmaxf(nbc + cn, 1e-12f));
        int o0 = atomicMax(&g_ir_ap[jgc], __float_as_int(ap));
        int o1 = atomicMin(&g_ir_an[jgc], __float_as_int(an));
        asm volatile("" :: "v"(o0), "v"(o1));
    }

    // ---------------- fence-free last-block final loss ----------------
    // Wait own atomic RMWs (incl. returns) -> complete at coherence point.
    VM_WAIT(0);
    __syncthreads();
    volatile int* flag = (volatile int*)lds;   // rowbase reads all done
    if (tid == 0) flag[0] = (atomicAdd(g_cnt, 1) == 255);
    __syncthreads();
    if (!flag[0]) return;

    float s = 0.f;
    #pragma unroll
    for (int k = 0; k < 8; ++k) {
        const int i = k * 512 + tid;
        // RMW reads: per-location total order => sees all completed maxima
        const float ap  = __int_as_float(atomicOr(&g_rgb_ap[i], 0));
        const float an  = __int_as_float(atomicOr(&g_rgb_an[i], 0));
        const float ap2 = __int_as_float(atomicOr(&g_ir_ap[i], 0));
        const float an2 = __int_as_float(atomicOr(&g_ir_an[i], 0));
        s += fmaxf(0.f, MARGIN - (an - ap)) + fmaxf(0.f, MARGIN - (an2 - ap2));
    }
    #pragma unroll
    for (int off = 32; off > 0; off >>= 1) s += __shfl_down(s, off);
    float* wsum = (float*)(lds + 64);
    __syncthreads();
    if ((tid & 63) == 0) wsum[tid >> 6] = s;
    __syncthreads();
    if (tid == 0) {
        float t = 0.f;
        #pragma unroll
        for (int w = 0; w < 8; ++w) t += wsum[w];
        g_out[0] = t / 4096.0f;
    }
}

// ---------------------------------------------------------------------------
extern "C" void kernel_launch(void* const* d_in, const int* in_sizes, int n_in,
                              void* d_out, int out_size, void* d_ws, size_t ws_size,
                              hipStream_t stream) {
    (void)in_sizes; (void)n_in; (void)out_size; (void)ws_size;
    const float* input = (const float*)d_in[0];
    const int* tgt = (const int*)d_in[1];
    float* out = (float*)d_out;

    unsigned short* bf = (unsigned short*)d_ws;
    float* norms = (float*)(bf + (size_t)8192 * 1024);
    int* red = (int*)(norms + 8192);          // 16384 ints + 1 counter

    hipFuncSetAttribute((const void*)dist_kernel,
                        hipFuncAttributeMaxDynamicSharedMemorySize, 153600);

    prep_kernel<<<2048, 256, 0, stream>>>(input, bf, norms, red);
    dist_kernel<<<dim3(16, 16), 512, 153600, stream>>>(
        bf, bf + (size_t)4096 * 1024, norms, norms + 4096, tgt,
        red, red + 4096, red + 8192, red + 12288,
        red + 16384, out);
}

// Round 8
// 47.005 us; speedup vs baseline: 3.2322x; 1.0400x over previous
//
#include <hip/hip_runtime.h>

#define MARGIN 0.3f
#define INF_BITS 0x7f800000
#define NINF_BITS 0xff800000

typedef __attribute__((ext_vector_type(8))) short bf16x8;
typedef __attribute__((ext_vector_type(4))) float f32x4;

__device__ inline unsigned short f2bf(float x) {
    unsigned int u = __float_as_uint(x);
    unsigned int r = (u + 0x7fffu + ((u >> 16) & 1u)) >> 16;
    return (unsigned short)r;
}

__device__ __forceinline__ void gload16(const unsigned short* g, char* l) {
    __builtin_amdgcn_global_load_lds(
        (const __attribute__((address_space(1))) void*)g,
        (__attribute__((address_space(3))) void*)l, 16, 0, 0);
}

// stage one 128x64 half-tile: this thread's 2 chunks (rows r0 and r0+64)
__device__ __forceinline__ void stage_half(const unsigned short* g, char* l) {
    gload16(g, l);                 // row r0
    gload16(g + 65536, l + 8192);  // row r0+64
}

// ---------------------------------------------------------------------------
// Kernel 1: fp32 -> bf16 cast + per-row norms (wave per row) + red-array init.
// ---------------------------------------------------------------------------
__global__ void __launch_bounds__(256) prep_kernel(
    const float* __restrict__ in, unsigned short* __restrict__ bf,
    float* __restrict__ norms, int* __restrict__ red)
{
    const int wid = threadIdx.x >> 6, lane = threadIdx.x & 63;
    const int row = blockIdx.x * 4 + wid;
    const size_t base = (size_t)row * 1024;
    float s = 0.f;
    #pragma unroll
    for (int k = 0; k < 4; ++k) {
        const float4 v = ((const float4*)(in + base))[lane + 64 * k];
        s += v.x * v.x + v.y * v.y + v.z * v.z + v.w * v.w;
        ushort4 o;
        o.x = f2bf(v.x); o.y = f2bf(v.y); o.z = f2bf(v.z); o.w = f2bf(v.w);
        ((ushort4*)(bf + base))[lane + 64 * k] = o;
    }
    #pragma unroll
    for (int off = 32; off > 0; off >>= 1) s += __shfl_down(s, off);
    if (lane == 0) norms[row] = s;
    if (blockIdx.x < 64) {
        int i = blockIdx.x * 256 + threadIdx.x;   // 0..16383
        red[i] = ((i >> 12) & 1) ? INF_BITS : 0;
    }
}

// ---------------------------------------------------------------------------
// Kernel 2: 256x256-tile, 8-phase bf16 MFMA GEMM + fused masked reductions.
// B-fragments register-prefetched one K-tile ahead (reads spread 4/7/7/6).
// ---------------------------------------------------------------------------
#define VM_WAIT(n) asm volatile("s_waitcnt vmcnt(" #n ")" ::: "memory")

#define STAGE_A(h, kt, b) \
    stage_half(pA + (h)*131072 + ((kt) << 6), lds + (b)*65536 + (h)*16384 + tid*16)
#define STAGE_B(h, kt, b) \
    stage_half(pB + (h)*131072 + ((kt) << 6), lds + (b)*65536 + 32768 + (h)*16384 + tid*16)

// next-tile B-fragment prefetch (3/3/2 split, no top-level commas)
#define EB1(B0, B1, SB) \
    B0[0] = *(const bf16x8*)((SB) + swz0); \
    B1[0] = *(const bf16x8*)((SB) + swz1); \
    B0[1] = *(const bf16x8*)((SB) + 2048 + swz0);
#define EB2(B0, B1, SB) \
    B1[1] = *(const bf16x8*)((SB) + 2048 + swz1); \
    B0[2] = *(const bf16x8*)((SB) + 4096 + swz0); \
    B1[2] = *(const bf16x8*)((SB) + 4096 + swz1);
#define EB3(B0, B1, SB) \
    B0[3] = *(const bf16x8*)((SB) + 6144 + swz0); \
    B1[3] = *(const bf16x8*)((SB) + 6144 + swz1);

#define PHASE(qq, bc, BK0, BK1, EXTRA, STAGE_STMT, WAIT_STMT)                    \
  {                                                                              \
    const char* ab = lds + (bc) * 65536 + aoff + (2 * (qq)) * 2048;              \
    bf16x8 a0k0 = *(const bf16x8*)(ab + swz0);                                   \
    bf16x8 a0k1 = *(const bf16x8*)(ab + swz1);                                   \
    bf16x8 a1k0 = *(const bf16x8*)(ab + 2048 + swz0);                            \
    bf16x8 a1k1 = *(const bf16x8*)(ab + 2048 + swz1);                            \
    EXTRA                                                                        \
    STAGE_STMT;                                                                  \
    __builtin_amdgcn_s_barrier();                                                \
    asm volatile("s_waitcnt lgkmcnt(0)" ::: "memory");                           \
    __builtin_amdgcn_sched_barrier(0);                                           \
    __builtin_amdgcn_s_setprio(1);                                               \
    _Pragma("unroll")                                                            \
    for (int n = 0; n < 4; ++n) {                                                \
      acc[2*(qq)][n]   = __builtin_amdgcn_mfma_f32_16x16x32_bf16(a0k0, BK0[n], acc[2*(qq)][n], 0, 0, 0);   \
      acc[2*(qq)+1][n] = __builtin_amdgcn_mfma_f32_16x16x32_bf16(a1k0, BK0[n], acc[2*(qq)+1][n], 0, 0, 0); \
    }                                                                            \
    _Pragma("unroll")                                                            \
    for (int n = 0; n < 4; ++n) {                                                \
      acc[2*(qq)][n]   = __builtin_amdgcn_mfma_f32_16x16x32_bf16(a0k1, BK1[n], acc[2*(qq)][n], 0, 0, 0);   \
      acc[2*(qq)+1][n] = __builtin_amdgcn_mfma_f32_16x16x32_bf16(a1k1, BK1[n], acc[2*(qq)+1][n], 0, 0, 0); \
    }                                                                            \
    __builtin_amdgcn_s_setprio(0);                                               \
    WAIT_STMT;                                                                   \
    __builtin_amdgcn_s_barrier();                                                \
  }

__global__ void __launch_bounds__(512, 2) dist_kernel(
    const unsigned short* __restrict__ Abf, const unsigned short* __restrict__ Bbf,
    const float* __restrict__ na, const float* __restrict__ nb,
    const int* __restrict__ tgt,
    int* __restrict__ g_rgb_ap, int* __restrict__ g_rgb_an,
    int* __restrict__ g_ir_ap, int* __restrict__ g_ir_an)
{
    extern __shared__ char lds[];

    const int tid  = threadIdx.x;
    const int lane = tid & 63;
    const int wid  = tid >> 6;          // 0..7
    const int wr   = wid >> 2;          // 0..1  (M)
    const int wc   = wid & 3;           // 0..3  (N)
    const int l4 = lane >> 4, rsel = lane & 15;

    // XCD-bijective swizzle: each XCD gets a 4(brow) x 8(bcol) region.
    const int lin = blockIdx.y * 16 + blockIdx.x;
    const int xcd = lin & 7, idx = lin >> 3;
    const int brow = (xcd >> 1) * 4 + (idx >> 3);
    const int bcol = (xcd & 1) * 8 + (idx & 7);

    // staging addresses (swizzle on the GLOBAL source column; LDS linear)
    const int r0 = tid >> 3;
    const int cs = (tid & 7) << 4;
    const int c0 = (cs ^ ((r0 & 7) << 4)) >> 1;
    const unsigned short* pA = Abf + (size_t)(brow * 256 + r0) * 1024 + c0;
    const unsigned short* pB = Bbf + (size_t)(bcol * 256 + r0) * 1024 + c0;

    // ds_read offsets (swizzled to match)
    const int swz0 = ((l4 ^ (rsel & 7)) << 4);
    const int swz1 = (((4 + l4) ^ (rsel & 7)) << 4);
    const int aoff = wr * 16384 + rsel * 128;
    const int boff = 32768 + (wc >> 1) * 16384 + (wc & 1) * 8192 + rsel * 128;
    const char* bB0 = lds + boff;            // B region of buf0
    const char* bB1 = lds + 65536 + boff;    // B region of buf1

    f32x4 acc[8][4];
    const f32x4 zero = {0.f, 0.f, 0.f, 0.f};
    #pragma unroll
    for (int m = 0; m < 8; ++m)
        #pragma unroll
        for (int n = 0; n < 4; ++n)
            acc[m][n] = zero;

    bf16x8 bkA0[4], bkA1[4], bkB0[4], bkB1[4];

    // prologue: K0 full -> buf0, K1 B-halves -> buf1; drain K0, leave B(1)
    STAGE_A(0, 0, 0); STAGE_A(1, 0, 0);
    STAGE_B(0, 0, 0); STAGE_B(1, 0, 0);
    STAGE_B(0, 1, 1); STAGE_B(1, 1, 1);
    VM_WAIT(4);
    __builtin_amdgcn_s_barrier();

    // pre-read B(0) fragments into bkA (resident in buf0)
    #pragma unroll
    for (int n = 0; n < 4; ++n) {
        bkA0[n] = *(const bf16x8*)(bB0 + n * 2048 + swz0);
        bkA1[n] = *(const bf16x8*)(bB0 + n * 2048 + swz1);
    }

    // main loop: tiles 0..13; B(t+1) prefetched into the other reg set.
    // Ledger per group: ph0 VM_WAIT(2) completes B(t+1) (issued >=4 phases
    // earlier); ph3 VM_WAIT(4) completes A-halves, leaves next B in flight.
    for (int i = 0; i < 7; ++i) {
        const int t = 2 * i;
        PHASE(0, 0, bkA0, bkA1, , STAGE_A(0, t + 1, 1), VM_WAIT(2));
        PHASE(1, 0, bkA0, bkA1, EB1(bkB0, bkB1, bB1), STAGE_A(1, t + 1, 1), );
        PHASE(2, 0, bkA0, bkA1, EB2(bkB0, bkB1, bB1), STAGE_B(0, t + 2, 0), );
        PHASE(3, 0, bkA0, bkA1, EB3(bkB0, bkB1, bB1), STAGE_B(1, t + 2, 0), VM_WAIT(4));
        PHASE(0, 1, bkB0, bkB1, , STAGE_A(0, t + 2, 0), VM_WAIT(2));
        PHASE(1, 1, bkB0, bkB1, EB1(bkA0, bkA1, bB0), STAGE_A(1, t + 2, 0), );
        PHASE(2, 1, bkB0, bkB1, EB2(bkA0, bkA1, bB0), STAGE_B(0, t + 3, 1), );
        PHASE(3, 1, bkB0, bkB1, EB3(bkA0, bkA1, bB0), STAGE_B(1, t + 3, 1), VM_WAIT(4));
    }

    // tail: tile 14 (stage+prefetch B(15)), tile 15 (pure compute)
    PHASE(0, 0, bkA0, bkA1, , STAGE_A(0, 15, 1), VM_WAIT(2));
    PHASE(1, 0, bkA0, bkA1, EB1(bkB0, bkB1, bB1), STAGE_A(1, 15, 1), );
    PHASE(2, 0, bkA0, bkA1, EB2(bkB0, bkB1, bB1), , );
    PHASE(3, 0, bkA0, bkA1, EB3(bkB0, bkB1, bB1), , VM_WAIT(0));
    PHASE(0, 1, bkB0, bkB1, , , );
    PHASE(1, 1, bkB0, bkB1, , , );
    PHASE(2, 1, bkB0, bkB1, , , );
    PHASE(3, 1, bkB0, bkB1, , , );

    // ---------------- fused epilogue (sq-space reductions) ----------------
    __syncthreads();

    char* rowbase = lds;                       // 256*528 = 135168 B
    float* colMax = (float*)(lds + 135168);    // 9216 B
    float* colMin = (float*)(lds + 144384);    // 9216 B

    const float NINF = __int_as_float((int)NINF_BITS);
    const float PINF = __int_as_float(INF_BITS);

    int jg[4], ltc[4];
    float nbv[4];
    #pragma unroll
    for (int n = 0; n < 4; ++n) {
        jg[n] = bcol * 256 + wc * 64 + n * 16 + rsel;
        ltc[n] = tgt[jg[n]];
        nbv[n] = nb[jg[n]];
    }

    float cmax[4] = {NINF, NINF, NINF, NINF};
    float cmin[4] = {PINF, PINF, PINF, PINF};

    #pragma unroll
    for (int m = 0; m < 8; ++m) {
        #pragma unroll
        for (int r = 0; r < 4; ++r) {
            const int lrow = wr * 128 + m * 16 + l4 * 4 + r;
            const int ig = brow * 256 + lrow;
            const int lt = tgt[4096 + ig];
            const float nav = na[ig];
            float rx = NINF, rn = PINF;
            #pragma unroll
            for (int n = 0; n < 4; ++n) {
                const float urow = __builtin_fmaf(-2.0f, acc[m][n][r], nbv[n]);
                const float ucol = __builtin_fmaf(-2.0f, acc[m][n][r], nav);
                const bool match = (ltc[n] == lt);
                rx = match ? fmaxf(rx, urow) : rx;
                rn = match ? rn : fminf(rn, urow);
                cmax[n] = match ? fmaxf(cmax[n], ucol) : cmax[n];
                cmin[n] = match ? cmin[n] : fminf(cmin[n], ucol);
            }
            float2* rp = (float2*)(rowbase + lrow * 528 + (wc * 16 + rsel) * 8);
            *rp = make_float2(rx, rn);
        }
    }
    #pragma unroll
    for (int n = 0; n < 4; ++n) {
        const int lcol = wc * 64 + n * 16 + rsel;
        colMax[lcol * 9 + wr * 4 + l4] = cmax[n];
        colMin[lcol * 9 + wr * 4 + l4] = cmin[n];
    }
    __syncthreads();

    if (tid < 256) {
        // row reduce: partials are (nb_j - 2dot); add na, clip, sqrt, atomic
        const int row = tid;
        const f32x4* rp = (const f32x4*)(rowbase + row * 528);
        float rmax = NINF, rmin = PINF;
        #pragma unroll 8
        for (int s = 0; s < 32; ++s) {
            const f32x4 v = rp[s];
            rmax = fmaxf(rmax, fmaxf(v[0], v[2]));
            rmin = fminf(rmin, fminf(v[1], v[3]));
        }
        const int ig = brow * 256 + row;
        const float nav = na[ig];
        const float ap = sqrtf(fmaxf(nav + rmax, 1e-12f));
        const float an = sqrtf(fmaxf(nav + rmin, 1e-12f));
        atomicMax(&g_rgb_ap[ig], __float_as_int(ap));
        atomicMin(&g_rgb_an[ig], __float_as_int(an));
    } else {
        // col reduce: partials are (na_i - 2dot); add nb, clip, sqrt, atomic
        const int col = tid & 255;
        float cm = NINF, cn = PINF;
        #pragma unroll
        for (int s = 0; s < 8; ++s) {
            cm = fmaxf(cm, colMax[col * 9 + s]);
            cn = fminf(cn, colMin[col * 9 + s]);
        }
        const int jgc = bcol * 256 + col;
        const float nbc = nb[jgc];
        const float ap = sqrtf(fmaxf(nbc + cm, 1e-12f));
        const float an = sqrtf(fmaxf(nbc + cn, 1e-12f));
        atomicMax(&g_ir_ap[jgc], __float_as_int(ap));
        atomicMin(&g_ir_an[jgc], __float_as_int(an));
    }
}

// ---------------------------------------------------------------------------
// Kernel 3: final loss (int4-vectorized single block).
// ---------------------------------------------------------------------------
__global__ void __launch_bounds__(256) loss_kernel(
    const int* __restrict__ red, float* __restrict__ out)
{
    float s = 0.f;
    const int t = threadIdx.x;
    #pragma unroll
    for (int k = 0; k < 4; ++k) {
        const int idx = k * 256 + t;
        const int4 ap  = ((const int4*)(red))[idx];
        const int4 an  = ((const int4*)(red + 4096))[idx];
        const int4 ap2 = ((const int4*)(red + 8192))[idx];
        const int4 an2 = ((const int4*)(red + 12288))[idx];
        s += fmaxf(0.f, MARGIN - (__int_as_float(an.x) - __int_as_float(ap.x)));
        s += fmaxf(0.f, MARGIN - (__int_as_float(an.y) - __int_as_float(ap.y)));
        s += fmaxf(0.f, MARGIN - (__int_as_float(an.z) - __int_as_float(ap.z)));
        s += fmaxf(0.f, MARGIN - (__int_as_float(an.w) - __int_as_float(ap.w)));
        s += fmaxf(0.f, MARGIN - (__int_as_float(an2.x) - __int_as_float(ap2.x)));
        s += fmaxf(0.f, MARGIN - (__int_as_float(an2.y) - __int_as_float(ap2.y)));
        s += fmaxf(0.f, MARGIN - (__int_as_float(an2.z) - __int_as_float(ap2.z)));
        s += fmaxf(0.f, MARGIN - (__int_as_float(an2.w) - __int_as_float(ap2.w)));
    }
    #pragma unroll
    for (int off = 32; off > 0; off >>= 1) s += __shfl_down(s, off);
    __shared__ float wsum[4];
    if ((threadIdx.x & 63) == 0) wsum[threadIdx.x >> 6] = s;
    __syncthreads();
    if (threadIdx.x == 0) out[0] = (wsum[0] + wsum[1] + wsum[2] + wsum[3]) / 4096.0f;
}

// ---------------------------------------------------------------------------
extern "C" void kernel_launch(void* const* d_in, const int* in_sizes, int n_in,
                              void* d_out, int out_size, void* d_ws, size_t ws_size,
                              hipStream_t stream) {
    (void)in_sizes; (void)n_in; (void)out_size; (void)ws_size;
    const float* input = (const float*)d_in[0];
    const int* tgt = (const int*)d_in[1];
    float* out = (float*)d_out;

    unsigned short* bf = (unsigned short*)d_ws;
    float* norms = (float*)(bf + (size_t)8192 * 1024);
    int* red = (int*)(norms + 8192);

    hipFuncSetAttribute((const void*)dist_kernel,
                        hipFuncAttributeMaxDynamicSharedMemorySize, 153600);

    prep_kernel<<<2048, 256, 0, stream>>>(input, bf, norms, red);
    dist_kernel<<<dim3(16, 16), 512, 153600, stream>>>(
        bf, bf + (size_t)4096 * 1024, norms, norms + 4096, tgt,
        red, red + 4096, red + 8192, red + 12288);
    loss_kernel<<<1, 256, 0, stream>>>(red, out);
}